// Round 6
// baseline (622.038 us; speedup 1.0000x reference)
//
#include <hip/hip_runtime.h>
#include <hip/hip_bf16.h>
#include <cstdint>
#include <cfloat>
#include <math.h>

// Problem constants (fixed by the reference)
#define NN 4096      // rows
#define DD 256       // embedding dim
#define NNEG 4092    // negatives per row
#define MARGIN 0.5f
#define NB 3584      // counting-sort buckets (14 per thread; 2 per LDS word)
#define NW (NB / 2)  // packed words

// ---------------------------------------------------------------------------
// JAX threefry2x32, key = jax.random.key(42) -> (0, 42). Partitionable mode:
// counter (hi=0, lo=i), bits = o0 ^ o1. (verified bit-exact: absmax 0.0 R2-R5)
// ---------------------------------------------------------------------------
__device__ __forceinline__ uint32_t rotl32(uint32_t x, int r) {
  return (x << r) | (x >> (32 - r));
}

__device__ __forceinline__ void threefry2x32_42(uint32_t x0, uint32_t x1,
                                                uint32_t& o0, uint32_t& o1) {
  const uint32_t k0 = 0u, k1 = 42u;
  const uint32_t k2 = k0 ^ k1 ^ 0x1BD11BDAu;
  x0 += k0; x1 += k1;
#define TF_R(r) { x0 += x1; x1 = rotl32(x1, r); x1 ^= x0; }
  TF_R(13) TF_R(15) TF_R(26) TF_R(6)
  x0 += k1; x1 += k2 + 1u;
  TF_R(17) TF_R(29) TF_R(16) TF_R(24)
  x0 += k2; x1 += k0 + 2u;
  TF_R(13) TF_R(15) TF_R(26) TF_R(6)
  x0 += k0; x1 += k1 + 3u;
  TF_R(17) TF_R(29) TF_R(16) TF_R(24)
  x0 += k1; x1 += k2 + 4u;
  TF_R(13) TF_R(15) TF_R(26) TF_R(6)
  x0 += k2; x1 += k0 + 5u;
#undef TF_R
  o0 = x0; o1 = x1;
}

// __logf swap: hw v_log_f32 (rel err ~2e-6) only affects ORDERING of scores in
// astronomically-rare near-ties; selected values (not scores) feed the outputs.
__device__ __forceinline__ float gumbel_at(uint32_t f) {
  uint32_t o0, o1;
  threefry2x32_42(0u, f, o0, o1);
  uint32_t bits = o0 ^ o1;
  uint32_t fb = (bits >> 9) | 0x3F800000u;
  float fl = __uint_as_float(fb) - 1.0f;
  float u = fmaxf(1e-20f, fl + 1e-20f);
  return -__logf(-__logf(u));
}

__device__ __forceinline__ int bucket_of(float v) {
  return (int)fminf(fmaxf((v + 0.5f) * (float)NB, 0.0f), (float)(NB - 1));
}

// ---------------------------------------------------------------------------
// Symmetric GEMM: S = X * X^T. Upper-triangle 128x128 blocks; double-buffered
// LDS + register prefetch, 1 barrier/kb. Grid-limited to ~2 blocks/CU, so the
// pipeline (not occupancy) hides global-load latency. k-accumulation order
// identical to R2-R5 (kb asc, k+=4, .x.y.z.w) -> sims bit-exact.
// ---------------------------------------------------------------------------
#define BT 128
#define NT (NN / BT)   // 32 -> 528 upper-triangle blocks
#define BK 32
#define LDSS 36        // padded LDS row stride (dwords): 2-way bank alias = free

__global__ __launch_bounds__(256) void gemm_sim(const float* __restrict__ X,
                                                float* __restrict__ S) {
  __shared__ float As[2][BT * LDSS];
  __shared__ float Bs[2][BT * LDSS];
  const int tid = threadIdx.x;
  const int tx = tid & 15, ty = tid >> 4;

  // decode linear upper-triangle index -> (bi, bj), bi <= bj
  int b = blockIdx.x, bi = 0;
  while (b >= NT - bi) { b -= NT - bi; bi++; }
  const int bj = bi + b;
  const int rowBase = bi * BT, colBase = bj * BT;

  int r_[4], c_[4];
  float4 av[4], bv[4];
#pragma unroll
  for (int it = 0; it < 4; ++it) {
    int idx = tid + 256 * it;            // 1024 float4 slots: 128 rows x 8
    r_[it] = idx >> 3;
    c_[it] = (idx & 7) * 4;
    av[it] = *(const float4*)(X + (size_t)(rowBase + r_[it]) * DD + c_[it]);
    bv[it] = *(const float4*)(X + (size_t)(colBase + r_[it]) * DD + c_[it]);
  }
#pragma unroll
  for (int it = 0; it < 4; ++it) {
    *(float4*)(&As[0][r_[it] * LDSS + c_[it]]) = av[it];
    *(float4*)(&Bs[0][r_[it] * LDSS + c_[it]]) = bv[it];
  }
  __syncthreads();

  float acc[8][8] = {};
  int cur = 0;
  for (int kbi = 0; kbi < DD / BK; ++kbi) {
    // prefetch next K-slab into registers (overlaps with compute below)
    if (kbi + 1 < DD / BK) {
      int kb = (kbi + 1) * BK;
#pragma unroll
      for (int it = 0; it < 4; ++it) {
        av[it] = *(const float4*)(X + (size_t)(rowBase + r_[it]) * DD + kb + c_[it]);
        bv[it] = *(const float4*)(X + (size_t)(colBase + r_[it]) * DD + kb + c_[it]);
      }
    }
    // compute current slab
    const float* Ac = As[cur];
    const float* Bc = Bs[cur];
#pragma unroll
    for (int k = 0; k < BK; k += 4) {
      float4 a[8], bfr[8];
#pragma unroll
      for (int i = 0; i < 8; ++i) a[i] = *(const float4*)(Ac + (ty + 16 * i) * LDSS + k);
#pragma unroll
      for (int j = 0; j < 8; ++j) bfr[j] = *(const float4*)(Bc + (tx + 16 * j) * LDSS + k);
#pragma unroll
      for (int i = 0; i < 8; ++i)
#pragma unroll
        for (int j = 0; j < 8; ++j) {
          acc[i][j] += a[i].x * bfr[j].x;
          acc[i][j] += a[i].y * bfr[j].y;
          acc[i][j] += a[i].z * bfr[j].z;
          acc[i][j] += a[i].w * bfr[j].w;
        }
    }
    // stage prefetched slab into the other buffer; single barrier per iter
    if (kbi + 1 < DD / BK) {
      int nxt = cur ^ 1;
#pragma unroll
      for (int it = 0; it < 4; ++it) {
        *(float4*)(&As[nxt][r_[it] * LDSS + c_[it]]) = av[it];
        *(float4*)(&Bs[nxt][r_[it] * LDSS + c_[it]]) = bv[it];
      }
      __syncthreads();
      cur = nxt;
    }
  }
#pragma unroll
  for (int i = 0; i < 8; ++i)
#pragma unroll
    for (int j = 0; j < 8; ++j)
      S[(size_t)(rowBase + ty + 16 * i) * NN + colBase + tx + 16 * j] = acc[i][j];
  if (bi != bj) {
#pragma unroll
    for (int i = 0; i < 8; ++i)
#pragma unroll
      for (int j = 0; j < 8; ++j)
        S[(size_t)(colBase + tx + 16 * j) * NN + rowBase + ty + 16 * i] = acc[i][j];
  }
}

// ---------------------------------------------------------------------------
// Per-row kernel v5: packed 16-bit hist with offs ALIASED onto it (23.5 KB LDS
// -> 6 blocks/CU). After scatter, word = bucket END; start(b) = end(b-1).
// ---------------------------------------------------------------------------
#define INSERT3(sc, v)                                              \
  if ((sc) > s2) {                                                  \
    if ((sc) > s1) {                                                \
      s2 = s1; v2 = v1;                                             \
      if ((sc) > s0) { s1 = s0; v1 = v0; s0 = (sc); v0 = (v); }     \
      else           { s1 = (sc); v1 = (v); }                       \
    } else { s2 = (sc); v2 = (v); }                                 \
  }

__global__ __launch_bounds__(256) void row_kernel(const float* __restrict__ S,
                                                  float* __restrict__ acc) {
  __shared__ uint32_t histw[NW];  // counts -> (after scan) cursors -> bucket ends
  __shared__ float sval[NN];      // values scattered by bucket
  __shared__ float sh[48];        // 0..2 pos sorted, 3 mu, 4 inv2s2,
                                  // 5..8 mean partials, 9 neg sum,
                                  // 10..13 var partials, 16..19 raw pos,
                                  // 24..47 wave top-3 (s,v)x3x4
  __shared__ uint32_t wtot[4];

  const int row = blockIdx.x;
  const int tid = threadIdx.x;
  const int lane = tid & 63, wid = tid >> 6;

  // zero histogram: 7 words/thread, stride 256 -> conflict-free
#pragma unroll
  for (int i = 0; i < 7; ++i) histw[tid + 256 * i] = 0u;

  // load 16 elements (coalesced float4), capture positives, poison class block
  const float4* src = (const float4*)(S + (size_t)row * NN);
  const int pslot = row >> 2;
  float vv[16];
#pragma unroll
  for (int it = 0; it < 4; ++it) {
    int slot = tid + 256 * it;
    float4 t4 = src[slot];
    if (slot == pslot) {
      sh[16] = t4.x; sh[17] = t4.y; sh[18] = t4.z; sh[19] = t4.w;
      t4.x = INFINITY; t4.y = INFINITY; t4.z = INFINITY; t4.w = INFINITY;
    }
    vv[4 * it + 0] = t4.x; vv[4 * it + 1] = t4.y;
    vv[4 * it + 2] = t4.z; vv[4 * it + 3] = t4.w;
  }

  // mean partial sums (skip infs)
  float s = 0.0f;
#pragma unroll
  for (int e = 0; e < 16; ++e) if (vv[e] < 1e30f) s += vv[e];
#pragma unroll
  for (int off = 32; off > 0; off >>= 1) s += __shfl_down(s, off, 64);
  if (lane == 0) sh[5 + wid] = s;
  __syncthreads();   // B1: hist zeroed, mean partials, raw pos visible

  // histogram (packed halves; counts <= 4096 so no carry between halves)
#pragma unroll
  for (int e = 0; e < 16; ++e) {
    int b = bucket_of(vv[e]);
    atomicAdd(&histw[b >> 1], 1u << ((b & 1) << 4));
  }
  if (tid == 0) {
    int self = row & 3;
    float p[3]; int m = 0;
#pragma unroll
    for (int c = 0; c < 4; ++c)
      if (c != self) p[m++] = sh[16 + c];
    float t;
    if (p[0] > p[1]) { t = p[0]; p[0] = p[1]; p[1] = t; }
    if (p[1] > p[2]) { t = p[1]; p[1] = p[2]; p[2] = t; }
    if (p[0] > p[1]) { t = p[0]; p[0] = p[1]; p[1] = t; }
    sh[0] = p[0]; sh[1] = p[1]; sh[2] = p[2];
    float tot = sh[5] + sh[6] + sh[7] + sh[8];
    sh[9] = tot;
    sh[3] = tot / (float)NNEG;
  }
  __syncthreads();   // B2: hist complete, mu visible

  // block exclusive prefix over NB buckets (14 buckets = 7 words per thread).
  // Each thread reads ONLY its own 7 words, so overwriting them with cursor
  // values later (same array) has no cross-thread hazard.
  uint32_t hw[7];
  uint32_t s14 = 0;
#pragma unroll
  for (int j = 0; j < 7; ++j) {
    hw[j] = histw[7 * tid + j];
    s14 += (hw[j] & 0xFFFFu) + (hw[j] >> 16);
  }
  uint32_t inc = s14;
#pragma unroll
  for (int off = 1; off < 64; off <<= 1) {
    uint32_t n = __shfl_up(inc, (unsigned)off, 64);
    if (lane >= off) inc += n;
  }
  if (lane == 63) wtot[wid] = inc;

  // variance partial sums (two-pass; mu from B2)
  const float mu = sh[3];
  float q = 0.0f;
#pragma unroll
  for (int e = 0; e < 16; ++e)
    if (vv[e] < 1e30f) { float d = vv[e] - mu; q += d * d; }
#pragma unroll
  for (int off = 32; off > 0; off >>= 1) q += __shfl_down(q, off, 64);
  if (lane == 0) sh[10 + wid] = q;
  __syncthreads();   // B3: wtot + var partials visible

  uint32_t wbase = 0;
  for (int w = 0; w < wid; ++w) wbase += wtot[w];
  uint32_t run = wbase + inc - s14;
#pragma unroll
  for (int j = 0; j < 7; ++j) {
    uint32_t lo = run; run += hw[j] & 0xFFFFu;
    uint32_t hi = run; run += hw[j] >> 16;
    histw[7 * tid + j] = lo | (hi << 16);   // overwrite counts with cursors
  }
  if (tid == 0) {
    float var = (sh[10] + sh[11] + sh[12] + sh[13]) / (float)NNEG;
    float sd = sqrtf(var);
    sh[4] = 1.0f / (2.0f * sd * sd);
  }
  __syncthreads();   // B4: cursors + inv2s2 ready

  // scatter (cursor -> end as a side effect)
#pragma unroll
  for (int e = 0; e < 16; ++e) {
    int b = bucket_of(vv[e]);
    uint32_t old = atomicAdd(&histw[b >> 1], 1u << ((b & 1) << 4));
    uint32_t sl = (old >> ((b & 1) << 4)) & 0xFFFFu;
    sval[sl] = vv[e];
  }
  __syncthreads();   // B5: scatter done (histw = bucket ends)

  // rank + score, slot-major (consecutive lanes -> same/nearby bucket).
  // start(b) = end(b-1); end(-1) = 0.
  const float inv2s2 = sh[4];
  const uint32_t fbase = (uint32_t)row * (uint32_t)NNEG;
  float s0 = -FLT_MAX, s1 = -FLT_MAX, s2 = -FLT_MAX;
  float v0 = 0.0f, v1 = 0.0f, v2 = 0.0f;
#pragma unroll 1
  for (int it = 0; it < 16; ++it) {
    int sl = tid + 256 * it;
    float v = sval[sl];
    if (v < 1e30f) {
      int b = bucket_of(v);
      uint32_t w = histw[b >> 1];
      uint32_t end, st;
      if (b & 1) { end = w >> 16; st = w & 0xFFFFu; }
      else {
        end = w & 0xFFFFu;
        st = (b == 0) ? 0u : (histw[(b >> 1) - 1] >> 16);
      }
      int cnt = (int)st;
      for (uint32_t u = st; u < end; ++u) {
        float wv = sval[u];
        cnt += (wv < v || (wv == v && (int)u < sl)) ? 1 : 0;
      }
      float d = v - mu;
      float sc = d * d * inv2s2 + gumbel_at(fbase + (uint32_t)cnt);
      INSERT3(sc, v)
    }
  }

  // wave butterfly top-3 merge (registers only)
#pragma unroll
  for (int dlt = 1; dlt < 64; dlt <<= 1) {
    float t0 = __shfl_xor(s0, dlt, 64), u0 = __shfl_xor(v0, dlt, 64);
    float t1 = __shfl_xor(s1, dlt, 64), u1 = __shfl_xor(v1, dlt, 64);
    float t2 = __shfl_xor(s2, dlt, 64), u2 = __shfl_xor(v2, dlt, 64);
    INSERT3(t0, u0)
    INSERT3(t1, u1)
    INSERT3(t2, u2)
  }
  if (lane == 0) {
    int b0 = 24 + wid * 6;
    sh[b0 + 0] = s0; sh[b0 + 1] = v0;
    sh[b0 + 2] = s1; sh[b0 + 3] = v1;
    sh[b0 + 4] = s2; sh[b0 + 5] = v2;
  }
  __syncthreads();   // B6: wave top-3s in sh

  if (tid == 0) {
    float g0 = -FLT_MAX, g1 = -FLT_MAX, g2 = -FLT_MAX;
    float w0 = 0.0f, w1 = 0.0f, w2 = 0.0f;
    {
      float s0 = g0, s1 = g1, s2 = g2, v0 = w0, v1 = w1, v2 = w2;
#pragma unroll
      for (int i = 0; i < 12; ++i) {
        float sc = sh[24 + 2 * i], v = sh[24 + 2 * i + 1];
        INSERT3(sc, v)
      }
      g0 = s0; g1 = s1; g2 = s2; w0 = v0; w1 = v1; w2 = v2;
    }
    float negmax = fmaxf(w0, fmaxf(w1, w2));
    float neg_loss = 0.04f * (log1pf(expf(50.0f * (w0 - MARGIN))) +
                              log1pf(expf(50.0f * (w1 - MARGIN))) +
                              log1pf(expf(50.0f * (w2 - MARGIN)))) / 3.0f;
    float p0 = sh[0], p1 = sh[1], p2 = sh[2];
    float pos_loss = (log1pf(expf(-2.0f * (p0 - MARGIN))) +
                      log1pf(expf(-2.0f * (p1 - MARGIN))) +
                      log1pf(expf(-2.0f * (p2 - MARGIN)))) / 3.0f;
    atomicAdd(&acc[0], pos_loss + neg_loss);
    if (p2 > negmax + 0.05f) atomicAdd(&acc[1], 1.0f);
    atomicAdd(&acc[2], p0 + p1 + p2);
    atomicAdd(&acc[3], sh[9]);
  }
}

// ---------------------------------------------------------------------------
__global__ void finalize(const float* __restrict__ acc, float* out) {
  if (threadIdx.x == 0 && blockIdx.x == 0) {
    out[0] = acc[0] / 4096.0f;                    // loss
    out[1] = acc[1] / 4096.0f;                    // prec
    out[2] = acc[2] / (4096.0f * 3.0f);           // pos_d
    out[3] = acc[3] / (4096.0f * 4092.0f);        // neg_d
  }
}

extern "C" void kernel_launch(void* const* d_in, const int* in_sizes, int n_in,
                              void* d_out, int out_size, void* d_ws, size_t ws_size,
                              hipStream_t stream) {
  (void)in_sizes; (void)n_in; (void)out_size; (void)ws_size;
  const float* X = (const float*)d_in[0];
  float* S = (float*)d_ws;                                   // 64 MB sim matrix
  float* acc = (float*)((char*)d_ws + (size_t)NN * NN * 4);  // 4 f32 accumulators
  hipMemsetAsync(acc, 0, 4 * sizeof(float), stream);
  gemm_sim<<<NT * (NT + 1) / 2, 256, 0, stream>>>(X, S);
  row_kernel<<<NN, 256, 0, stream>>>(S, acc);
  finalize<<<1, 64, 0, stream>>>(acc, (float*)d_out);
}

// Round 7
// 375.307 us; speedup vs baseline: 1.6574x; 1.6574x over previous
//
#include <hip/hip_runtime.h>
#include <hip/hip_bf16.h>
#include <cstdint>
#include <cfloat>
#include <math.h>

// Problem constants (fixed by the reference)
#define NN 4096      // rows
#define DD 256       // embedding dim
#define NNEG 4092    // negatives per row
#define MARGIN 0.5f
#define NB 3584      // counting-sort buckets (14 per thread; 2 per LDS word)
#define NW (NB / 2)  // packed words

// ---------------------------------------------------------------------------
// JAX threefry2x32, key = jax.random.key(42) -> (0, 42). Partitionable mode:
// counter (hi=0, lo=i), bits = o0 ^ o1. (verified bit-exact: absmax 0.0 R2-R6)
// ---------------------------------------------------------------------------
__device__ __forceinline__ uint32_t rotl32(uint32_t x, int r) {
  return (x << r) | (x >> (32 - r));
}

__device__ __forceinline__ void threefry2x32_42(uint32_t x0, uint32_t x1,
                                                uint32_t& o0, uint32_t& o1) {
  const uint32_t k0 = 0u, k1 = 42u;
  const uint32_t k2 = k0 ^ k1 ^ 0x1BD11BDAu;
  x0 += k0; x1 += k1;
#define TF_R(r) { x0 += x1; x1 = rotl32(x1, r); x1 ^= x0; }
  TF_R(13) TF_R(15) TF_R(26) TF_R(6)
  x0 += k1; x1 += k2 + 1u;
  TF_R(17) TF_R(29) TF_R(16) TF_R(24)
  x0 += k2; x1 += k0 + 2u;
  TF_R(13) TF_R(15) TF_R(26) TF_R(6)
  x0 += k0; x1 += k1 + 3u;
  TF_R(17) TF_R(29) TF_R(16) TF_R(24)
  x0 += k1; x1 += k2 + 4u;
  TF_R(13) TF_R(15) TF_R(26) TF_R(6)
  x0 += k2; x1 += k0 + 5u;
#undef TF_R
  o0 = x0; o1 = x1;
}

// __logf: hw v_log_f32 (rel err ~2e-6) — only reorders scores in
// astronomically-rare near-ties; verified absmax 0.0 in R6.
__device__ __forceinline__ float gumbel_at(uint32_t f) {
  uint32_t o0, o1;
  threefry2x32_42(0u, f, o0, o1);
  uint32_t bits = o0 ^ o1;
  uint32_t fb = (bits >> 9) | 0x3F800000u;
  float fl = __uint_as_float(fb) - 1.0f;
  float u = fmaxf(1e-20f, fl + 1e-20f);
  return -__logf(-__logf(u));
}

__device__ __forceinline__ int bucket_of(float v) {
  return (int)fminf(fmaxf((v + 0.5f) * (float)NB, 0.0f), (float)(NB - 1));
}

// ---------------------------------------------------------------------------
// Symmetric GEMM: S = X * X^T. Upper-triangle 64x64 blocks (2080 blocks ->
// ~8/CU grid parallelism), BK=32, single-buffered, 18.4 KB LDS -> LDS allows
// 8 blocks/CU. 4x4 acc/thread keeps VGPR ~80 (no spills — R6's 256-VGPR
// register-prefetch spilled ~500 MB to scratch). k-accumulation order
// identical to R2-R6 (kb asc, k+=4, .x.y.z.w) -> sims bit-exact.
// ---------------------------------------------------------------------------
#define BT 64
#define NT (NN / BT)   // 64 -> 2080 upper-triangle blocks
#define BK 32
#define LDSS 36        // padded LDS row stride (dwords): 2-way bank alias free

__global__ __launch_bounds__(256) void gemm_sim(const float* __restrict__ X,
                                                float* __restrict__ S) {
  __shared__ float As[BT * LDSS];
  __shared__ float Bs[BT * LDSS];
  const int tid = threadIdx.x;
  const int tx = tid & 15, ty = tid >> 4;

  // decode linear upper-triangle index -> (bi, bj), bi <= bj
  int b = blockIdx.x, bi = 0;
  while (b >= NT - bi) { b -= NT - bi; bi++; }
  const int bj = bi + b;
  const int rowBase = bi * BT, colBase = bj * BT;

  float acc[4][4] = {};
  for (int kb = 0; kb < DD; kb += BK) {
#pragma unroll
    for (int it = 0; it < 2; ++it) {
      int idx = tid + 256 * it;            // 512 float4 slots: 64 rows x 8
      int r = idx >> 3, c4 = idx & 7;
      float4 av = *(const float4*)(X + (size_t)(rowBase + r) * DD + kb + c4 * 4);
      float4 bv = *(const float4*)(X + (size_t)(colBase + r) * DD + kb + c4 * 4);
      *(float4*)(As + r * LDSS + c4 * 4) = av;
      *(float4*)(Bs + r * LDSS + c4 * 4) = bv;
    }
    __syncthreads();
    for (int k = 0; k < BK; k += 4) {
      float4 a[4], bfr[4];
#pragma unroll
      for (int i = 0; i < 4; ++i) a[i] = *(const float4*)(As + (ty + 16 * i) * LDSS + k);
#pragma unroll
      for (int j = 0; j < 4; ++j) bfr[j] = *(const float4*)(Bs + (tx + 16 * j) * LDSS + k);
#pragma unroll
      for (int i = 0; i < 4; ++i)
#pragma unroll
        for (int j = 0; j < 4; ++j) {
          acc[i][j] += a[i].x * bfr[j].x;
          acc[i][j] += a[i].y * bfr[j].y;
          acc[i][j] += a[i].z * bfr[j].z;
          acc[i][j] += a[i].w * bfr[j].w;
        }
    }
    __syncthreads();
  }
#pragma unroll
  for (int i = 0; i < 4; ++i)
#pragma unroll
    for (int j = 0; j < 4; ++j)
      S[(size_t)(rowBase + ty + 16 * i) * NN + colBase + tx + 16 * j] = acc[i][j];
  if (bi != bj) {
#pragma unroll
    for (int i = 0; i < 4; ++i)
#pragma unroll
      for (int j = 0; j < 4; ++j)
        S[(size_t)(colBase + tx + 16 * j) * NN + rowBase + ty + 16 * i] = acc[i][j];
  }
}

// ---------------------------------------------------------------------------
// Per-row kernel v5 (unchanged from R6 — verified absmax 0.0, ~150 us):
// packed 16-bit hist with offs aliased onto it (23.5 KB LDS -> 6 blocks/CU).
// ---------------------------------------------------------------------------
#define INSERT3(sc, v)                                              \
  if ((sc) > s2) {                                                  \
    if ((sc) > s1) {                                                \
      s2 = s1; v2 = v1;                                             \
      if ((sc) > s0) { s1 = s0; v1 = v0; s0 = (sc); v0 = (v); }     \
      else           { s1 = (sc); v1 = (v); }                       \
    } else { s2 = (sc); v2 = (v); }                                 \
  }

__global__ __launch_bounds__(256) void row_kernel(const float* __restrict__ S,
                                                  float* __restrict__ acc) {
  __shared__ uint32_t histw[NW];  // counts -> cursors -> bucket ends
  __shared__ float sval[NN];      // values scattered by bucket
  __shared__ float sh[48];
  __shared__ uint32_t wtot[4];

  const int row = blockIdx.x;
  const int tid = threadIdx.x;
  const int lane = tid & 63, wid = tid >> 6;

#pragma unroll
  for (int i = 0; i < 7; ++i) histw[tid + 256 * i] = 0u;

  const float4* src = (const float4*)(S + (size_t)row * NN);
  const int pslot = row >> 2;
  float vv[16];
#pragma unroll
  for (int it = 0; it < 4; ++it) {
    int slot = tid + 256 * it;
    float4 t4 = src[slot];
    if (slot == pslot) {
      sh[16] = t4.x; sh[17] = t4.y; sh[18] = t4.z; sh[19] = t4.w;
      t4.x = INFINITY; t4.y = INFINITY; t4.z = INFINITY; t4.w = INFINITY;
    }
    vv[4 * it + 0] = t4.x; vv[4 * it + 1] = t4.y;
    vv[4 * it + 2] = t4.z; vv[4 * it + 3] = t4.w;
  }

  float s = 0.0f;
#pragma unroll
  for (int e = 0; e < 16; ++e) if (vv[e] < 1e30f) s += vv[e];
#pragma unroll
  for (int off = 32; off > 0; off >>= 1) s += __shfl_down(s, off, 64);
  if (lane == 0) sh[5 + wid] = s;
  __syncthreads();   // B1

#pragma unroll
  for (int e = 0; e < 16; ++e) {
    int b = bucket_of(vv[e]);
    atomicAdd(&histw[b >> 1], 1u << ((b & 1) << 4));
  }
  if (tid == 0) {
    int self = row & 3;
    float p[3]; int m = 0;
#pragma unroll
    for (int c = 0; c < 4; ++c)
      if (c != self) p[m++] = sh[16 + c];
    float t;
    if (p[0] > p[1]) { t = p[0]; p[0] = p[1]; p[1] = t; }
    if (p[1] > p[2]) { t = p[1]; p[1] = p[2]; p[2] = t; }
    if (p[0] > p[1]) { t = p[0]; p[0] = p[1]; p[1] = t; }
    sh[0] = p[0]; sh[1] = p[1]; sh[2] = p[2];
    float tot = sh[5] + sh[6] + sh[7] + sh[8];
    sh[9] = tot;
    sh[3] = tot / (float)NNEG;
  }
  __syncthreads();   // B2

  uint32_t hw[7];
  uint32_t s14 = 0;
#pragma unroll
  for (int j = 0; j < 7; ++j) {
    hw[j] = histw[7 * tid + j];
    s14 += (hw[j] & 0xFFFFu) + (hw[j] >> 16);
  }
  uint32_t inc = s14;
#pragma unroll
  for (int off = 1; off < 64; off <<= 1) {
    uint32_t n = __shfl_up(inc, (unsigned)off, 64);
    if (lane >= off) inc += n;
  }
  if (lane == 63) wtot[wid] = inc;

  const float mu = sh[3];
  float q = 0.0f;
#pragma unroll
  for (int e = 0; e < 16; ++e)
    if (vv[e] < 1e30f) { float d = vv[e] - mu; q += d * d; }
#pragma unroll
  for (int off = 32; off > 0; off >>= 1) q += __shfl_down(q, off, 64);
  if (lane == 0) sh[10 + wid] = q;
  __syncthreads();   // B3

  uint32_t wbase = 0;
  for (int w = 0; w < wid; ++w) wbase += wtot[w];
  uint32_t run = wbase + inc - s14;
#pragma unroll
  for (int j = 0; j < 7; ++j) {
    uint32_t lo = run; run += hw[j] & 0xFFFFu;
    uint32_t hi = run; run += hw[j] >> 16;
    histw[7 * tid + j] = lo | (hi << 16);   // counts -> cursors
  }
  if (tid == 0) {
    float var = (sh[10] + sh[11] + sh[12] + sh[13]) / (float)NNEG;
    float sd = sqrtf(var);
    sh[4] = 1.0f / (2.0f * sd * sd);
  }
  __syncthreads();   // B4

#pragma unroll
  for (int e = 0; e < 16; ++e) {
    int b = bucket_of(vv[e]);
    uint32_t old = atomicAdd(&histw[b >> 1], 1u << ((b & 1) << 4));
    uint32_t sl = (old >> ((b & 1) << 4)) & 0xFFFFu;
    sval[sl] = vv[e];
  }
  __syncthreads();   // B5: histw = bucket ends

  const float inv2s2 = sh[4];
  const uint32_t fbase = (uint32_t)row * (uint32_t)NNEG;
  float s0 = -FLT_MAX, s1 = -FLT_MAX, s2 = -FLT_MAX;
  float v0 = 0.0f, v1 = 0.0f, v2 = 0.0f;
#pragma unroll 1
  for (int it = 0; it < 16; ++it) {
    int sl = tid + 256 * it;
    float v = sval[sl];
    if (v < 1e30f) {
      int b = bucket_of(v);
      uint32_t w = histw[b >> 1];
      uint32_t end, st;
      if (b & 1) { end = w >> 16; st = w & 0xFFFFu; }
      else {
        end = w & 0xFFFFu;
        st = (b == 0) ? 0u : (histw[(b >> 1) - 1] >> 16);
      }
      int cnt = (int)st;
      for (uint32_t u = st; u < end; ++u) {
        float wv = sval[u];
        cnt += (wv < v || (wv == v && (int)u < sl)) ? 1 : 0;
      }
      float d = v - mu;
      float sc = d * d * inv2s2 + gumbel_at(fbase + (uint32_t)cnt);
      INSERT3(sc, v)
    }
  }

#pragma unroll
  for (int dlt = 1; dlt < 64; dlt <<= 1) {
    float t0 = __shfl_xor(s0, dlt, 64), u0 = __shfl_xor(v0, dlt, 64);
    float t1 = __shfl_xor(s1, dlt, 64), u1 = __shfl_xor(v1, dlt, 64);
    float t2 = __shfl_xor(s2, dlt, 64), u2 = __shfl_xor(v2, dlt, 64);
    INSERT3(t0, u0)
    INSERT3(t1, u1)
    INSERT3(t2, u2)
  }
  if (lane == 0) {
    int b0 = 24 + wid * 6;
    sh[b0 + 0] = s0; sh[b0 + 1] = v0;
    sh[b0 + 2] = s1; sh[b0 + 3] = v1;
    sh[b0 + 4] = s2; sh[b0 + 5] = v2;
  }
  __syncthreads();   // B6

  if (tid == 0) {
    float g0 = -FLT_MAX, g1 = -FLT_MAX, g2 = -FLT_MAX;
    float w0 = 0.0f, w1 = 0.0f, w2 = 0.0f;
    {
      float s0 = g0, s1 = g1, s2 = g2, v0 = w0, v1 = w1, v2 = w2;
#pragma unroll
      for (int i = 0; i < 12; ++i) {
        float sc = sh[24 + 2 * i], v = sh[24 + 2 * i + 1];
        INSERT3(sc, v)
      }
      g0 = s0; g1 = s1; g2 = s2; w0 = v0; w1 = v1; w2 = v2;
    }
    float negmax = fmaxf(w0, fmaxf(w1, w2));
    float neg_loss = 0.04f * (log1pf(expf(50.0f * (w0 - MARGIN))) +
                              log1pf(expf(50.0f * (w1 - MARGIN))) +
                              log1pf(expf(50.0f * (w2 - MARGIN)))) / 3.0f;
    float p0 = sh[0], p1 = sh[1], p2 = sh[2];
    float pos_loss = (log1pf(expf(-2.0f * (p0 - MARGIN))) +
                      log1pf(expf(-2.0f * (p1 - MARGIN))) +
                      log1pf(expf(-2.0f * (p2 - MARGIN)))) / 3.0f;
    atomicAdd(&acc[0], pos_loss + neg_loss);
    if (p2 > negmax + 0.05f) atomicAdd(&acc[1], 1.0f);
    atomicAdd(&acc[2], p0 + p1 + p2);
    atomicAdd(&acc[3], sh[9]);
  }
}

// ---------------------------------------------------------------------------
__global__ void finalize(const float* __restrict__ acc, float* out) {
  if (threadIdx.x == 0 && blockIdx.x == 0) {
    out[0] = acc[0] / 4096.0f;                    // loss
    out[1] = acc[1] / 4096.0f;                    // prec
    out[2] = acc[2] / (4096.0f * 3.0f);           // pos_d
    out[3] = acc[3] / (4096.0f * 4092.0f);        // neg_d
  }
}

extern "C" void kernel_launch(void* const* d_in, const int* in_sizes, int n_in,
                              void* d_out, int out_size, void* d_ws, size_t ws_size,
                              hipStream_t stream) {
  (void)in_sizes; (void)n_in; (void)out_size; (void)ws_size;
  const float* X = (const float*)d_in[0];
  float* S = (float*)d_ws;                                   // 64 MB sim matrix
  float* acc = (float*)((char*)d_ws + (size_t)NN * NN * 4);  // 4 f32 accumulators
  hipMemsetAsync(acc, 0, 4 * sizeof(float), stream);
  gemm_sim<<<NT * (NT + 1) / 2, 256, 0, stream>>>(X, S);
  row_kernel<<<NN, 256, 0, stream>>>(S, acc);
  finalize<<<1, 64, 0, stream>>>(acc, (float*)d_out);
}